// Round 5
// baseline (376.860 us; speedup 1.0000x reference)
//
#include <hip/hip_runtime.h>
#include <hip/hip_cooperative_groups.h>
#include <stdint.h>

namespace cg = cooperative_groups;

// out = dequant( int8(lhs*ls) @ int8(rhs*rs) ) / (ls*rs), 4096^3, fp32 in/out.
// Single cooperative mega-kernel: absmax -> grid.sync -> quant -> grid.sync ->
// int8 GEMM (2 tiles/block). Grid 512 blocks x 256 thr: cooperative launch
// needs only 2 blocks/CU co-resident (GEMM uses ~88 VGPR + 64 AGPR = ~152
// unified regs -> 3 blocks/CU cap; round-4's 1024-block/4-per-CU ask exceeded
// this and the launch silently failed). Per-block amax -> red[512]
// (slot-per-block, no atomics); every block recomputes identical scales
// (fmax is order-exact, so bit-identical across blocks).
//
// Workspace: [0,16Mi) qA int8 MxK ; [16Mi,32Mi) qBT int8 NxK ; [32Mi,+2Ki) red.

#define NROW 4096
#define NELEM (4096 * 4096)

typedef __attribute__((ext_vector_type(4))) int int32x4;
typedef const __attribute__((address_space(1))) int8_t* gptr1_t;
typedef __attribute__((address_space(3))) int8_t* lptr3_t;

__device__ __forceinline__ int q8(float v, float s) {
    int r = __float2int_rn(v * s);  // RNE, matches jnp.round
    r = r < -127 ? -127 : r;
    r = r > 127 ? 127 : r;
    return r;
}

__device__ __forceinline__ float max4(float4 v) {
    return fmaxf(fmaxf(fabsf(v.x), fabsf(v.y)), fmaxf(fabsf(v.z), fabsf(v.w)));
}

__global__ __launch_bounds__(256, 2) void mega_kernel(
    const float* __restrict__ lhs, const float* __restrict__ rhs,
    int8_t* __restrict__ qA, int8_t* __restrict__ qBT,
    float* __restrict__ out, float* __restrict__ red) {
    __shared__ __align__(16) int8_t smem[32768];
    cg::grid_group grid = cg::this_grid();

    const int tid = threadIdx.x;
    const int lane = tid & 63, wave = tid >> 6;
    const int bid = blockIdx.x;

    // ---- phase 1: per-block absmax (blocks 0..255 -> lhs, 256..511 -> rhs)
    {
        const float4* x4 = (const float4*)((bid >> 8) ? rhs : lhs);
        const int stride = 256 * 256;  // 65536 float4s; 64 strides cover tensor
        int i = (bid & 255) * 256 + tid;
        float m0 = 0, m1 = 0, m2 = 0, m3 = 0;
#pragma unroll 2
        for (int it = 0; it < 16; ++it, i += 4 * stride) {
            float4 a = x4[i];
            float4 b = x4[i + stride];
            float4 c = x4[i + 2 * stride];
            float4 d = x4[i + 3 * stride];
            m0 = fmaxf(m0, max4(a));
            m1 = fmaxf(m1, max4(b));
            m2 = fmaxf(m2, max4(c));
            m3 = fmaxf(m3, max4(d));
        }
        float m = fmaxf(fmaxf(m0, m1), fmaxf(m2, m3));
        for (int off = 32; off > 0; off >>= 1)
            m = fmaxf(m, __shfl_down(m, off, 64));
        float* r4 = (float*)smem;
        if (lane == 0) r4[wave] = m;
        __syncthreads();
        if (tid == 0) red[bid] = fmaxf(fmaxf(r4[0], r4[1]), fmaxf(r4[2], r4[3]));
        __syncthreads();
    }
    grid.sync();

    // ---- phase 2: scales (uniform across blocks) + quantize
    float sL, sR;
    {
        float vL = red[tid];        // lhs partials: red[0..255]
        float vR = red[tid + 256];  // rhs partials: red[256..511]
        for (int off = 32; off > 0; off >>= 1) {
            vL = fmaxf(vL, __shfl_down(vL, off, 64));
            vR = fmaxf(vR, __shfl_down(vR, off, 64));
        }
        float* r8 = (float*)smem;
        if (lane == 0) { r8[wave] = vL; r8[4 + wave] = vR; }
        __syncthreads();
        float amL = fmaxf(fmaxf(r8[0], r8[1]), fmaxf(r8[2], r8[3]));
        float amR = fmaxf(fmaxf(r8[4], r8[5]), fmaxf(r8[6], r8[7]));
        sL = 127.0f / fmaxf(amL, 1e-12f);
        sR = 127.0f / fmaxf(amR, 1e-12f);
        __syncthreads();
    }
    // quantize A straight (coalesced float4 -> packed dword)
    {
        int i = bid * 256 + tid;
#pragma unroll 4
        for (int it = 0; it < 32; ++it, i += 512 * 256) {
            float4 v = ((const float4*)lhs)[i];
            int b0 = q8(v.x, sL), b1 = q8(v.y, sL), b2 = q8(v.z, sL),
                b3 = q8(v.w, sL);
            ((int*)qA)[i] = (b0 & 0xff) | ((b1 & 0xff) << 8)
                          | ((b2 & 0xff) << 16) | ((b3 & 0xff) << 24);
        }
    }
    // quantize + transpose B via 64x64 LDS tiles, 8 tiles/block
    {
        int8_t(*sm)[68] = (int8_t(*)[68])smem;
        const int rl = tid >> 4, nq = tid & 15;
        const int nl = tid >> 2, kq = tid & 3;
        for (int j = 0; j < 8; ++j) {
            const int t = bid * 8 + j;
            const int n0 = (t & 63) * 64, k0 = (t >> 6) * 64;
#pragma unroll
            for (int r = 0; r < 4; ++r) {
                const int kl = r * 16 + rl;
                float4 v =
                    *(const float4*)(rhs + (size_t)(k0 + kl) * NROW + n0 + nq * 4);
                sm[nq * 4 + 0][kl] = (int8_t)q8(v.x, sR);
                sm[nq * 4 + 1][kl] = (int8_t)q8(v.y, sR);
                sm[nq * 4 + 2][kl] = (int8_t)q8(v.z, sR);
                sm[nq * 4 + 3][kl] = (int8_t)q8(v.w, sR);
            }
            __syncthreads();
            int4 w;
            w.x = *(const int*)&sm[nl][kq * 16 + 0];
            w.y = *(const int*)&sm[nl][kq * 16 + 4];
            w.z = *(const int*)&sm[nl][kq * 16 + 8];
            w.w = *(const int*)&sm[nl][kq * 16 + 12];
            *(int4*)(qBT + (size_t)(n0 + nl) * NROW + k0 + kq * 16) = w;
            __syncthreads();
        }
    }
    grid.sync();

    // ---- phase 3: two 128x128-tile int8 GEMMs, BK=128, mfma_i32_16x16x64_i8.
    // LDS swizzle: position p of row holds global 16B-quad (p - row) & 7 ->
    // conflict-free fragment reads, lane-contiguous global_load_lds staging.
    {
        int8_t* sA = smem;
        int8_t* sB = smem + 16384;
        const int wm = (wave & 1) * 64, wn = (wave >> 1) * 64;
        const float inv = 1.0f / (sL * sR);

        int rowS[4], gqS[4];
#pragma unroll
        for (int j = 0; j < 4; ++j) {
            const int c = tid + j * 256;
            rowS[j] = c >> 3;
            gqS[j] = ((c & 7) - rowS[j]) & 7;
        }
        const int q = lane >> 4;  // K-quad within 64
        const int r = lane & 15;  // row (A) / col (B) within 16

        for (int tt = 0; tt < 2; ++tt) {
            const int t = bid + tt * 512;
            const int m0 = (t >> 5) * 128, n0 = (t & 31) * 128;

            int32x4 acc[4][4];
#pragma unroll
            for (int mi = 0; mi < 4; ++mi)
#pragma unroll
                for (int ni = 0; ni < 4; ++ni) acc[mi][ni] = (int32x4)(0);

            for (int kt = 0; kt < 32; ++kt) {
                const int kb = kt * 128;
                __syncthreads();
#pragma unroll
                for (int j = 0; j < 4; ++j) {
                    const int c = tid + j * 256;
                    __builtin_amdgcn_global_load_lds(
                        (gptr1_t)(qA + (size_t)(m0 + rowS[j]) * NROW + kb +
                                  gqS[j] * 16),
                        (lptr3_t)(sA + c * 16), 16, 0, 0);
                    __builtin_amdgcn_global_load_lds(
                        (gptr1_t)(qBT + (size_t)(n0 + rowS[j]) * NROW + kb +
                                  gqS[j] * 16),
                        (lptr3_t)(sB + c * 16), 16, 0, 0);
                }
                __syncthreads();

#pragma unroll
                for (int kk = 0; kk < 2; ++kk) {
                    int32x4 af[4], bf[4];
#pragma unroll
                    for (int mi = 0; mi < 4; ++mi) {
                        const int row = wm + mi * 16 + r;
                        af[mi] = *(const int32x4*)(
                            sA + row * 128 + (((kk * 4 + q + row) & 7) * 16));
                    }
#pragma unroll
                    for (int ni = 0; ni < 4; ++ni) {
                        const int row = wn + ni * 16 + r;
                        bf[ni] = *(const int32x4*)(
                            sB + row * 128 + (((kk * 4 + q + row) & 7) * 16));
                    }
#pragma unroll
                    for (int mi = 0; mi < 4; ++mi)
#pragma unroll
                        for (int ni = 0; ni < 4; ++ni)
                            acc[mi][ni] = __builtin_amdgcn_mfma_i32_16x16x64_i8(
                                af[mi], bf[ni], acc[mi][ni], 0, 0, 0);
                }
            }

            // C/D layout: col = lane&15, row = (lane>>4)*4 + reg
#pragma unroll
            for (int mi = 0; mi < 4; ++mi)
#pragma unroll
                for (int ni = 0; ni < 4; ++ni)
#pragma unroll
                    for (int reg = 0; reg < 4; ++reg) {
                        const int row = m0 + wm + mi * 16 + q * 4 + reg;
                        const int col = n0 + wn + ni * 16 + r;
                        out[(size_t)row * NROW + col] =
                            (float)acc[mi][ni][reg] * inv;
                    }
        }
    }
}

extern "C" void kernel_launch(void* const* d_in, const int* in_sizes, int n_in,
                              void* d_out, int out_size, void* d_ws,
                              size_t ws_size, hipStream_t stream) {
    const float* lhs = (const float*)d_in[0];
    const float* rhs = (const float*)d_in[1];
    float* out = (float*)d_out;

    int8_t* qA = (int8_t*)d_ws;
    int8_t* qBT = qA + (size_t)16 * 1024 * 1024;
    float* red = (float*)(qBT + (size_t)16 * 1024 * 1024);

    void* args[] = {(void*)&lhs, (void*)&rhs, (void*)&qA,
                    (void*)&qBT, (void*)&out, (void*)&red};
    hipLaunchCooperativeKernel((void*)mega_kernel, dim3(512), dim3(256), args,
                               0, stream);
}